// Round 9
// baseline (324.767 us; speedup 1.0000x reference)
//
#include <hip/hip_runtime.h>
#include <math.h>

typedef __bf16 bf16x8 __attribute__((ext_vector_type(8)));
typedef __bf16 bf16x4 __attribute__((ext_vector_type(4)));
typedef float  f32x4  __attribute__((ext_vector_type(4)));

#define QL    32
#define DL    256
#define DIM   256
#define NK    21
#define KSOFT 20
#define STR   264                 // (fallback kernels only)
#define L2E   1.4426950408889634f

#if __has_builtin(__builtin_amdgcn_exp2f)
#define EXP2F(x) __builtin_amdgcn_exp2f(x)
#else
#define EXP2F(x) exp2f(x)
#endif

// ---------- Phase 1: stream-normalize emb -> bf16 table in ws (2 rows/wave) --
__global__ __launch_bounds__(256)
void knrm_prep(const float* __restrict__ emb, __bf16* __restrict__ tab, int V)
{
    const int wave = threadIdx.x >> 6;
    const int lane = threadIdx.x & 63;
    const int row0 = (blockIdx.x * 4 + wave) * 2;
    if (row0 >= V) return;                     // V even -> row0+1 also valid

    float4 a = reinterpret_cast<const float4*>(emb + (size_t)row0 * DIM)[lane];
    float4 c = reinterpret_cast<const float4*>(emb + (size_t)(row0 + 1) * DIM)[lane];
    float sa = a.x*a.x + a.y*a.y + a.z*a.z + a.w*a.w;
    float sc = c.x*c.x + c.y*c.y + c.z*c.z + c.w*c.w;
    #pragma unroll
    for (int m = 32; m; m >>= 1) { sa += __shfl_xor(sa, m); sc += __shfl_xor(sc, m); }
    float ia = rsqrtf(fmaxf(sa, 1e-16f));      // ||row|| ~16, ref eps never binds
    float ic = rsqrtf(fmaxf(sc, 1e-16f));
    bf16x4 oa, oc;
    oa[0] = (__bf16)(a.x * ia); oa[1] = (__bf16)(a.y * ia);
    oa[2] = (__bf16)(a.z * ia); oa[3] = (__bf16)(a.w * ia);
    oc[0] = (__bf16)(c.x * ic); oc[1] = (__bf16)(c.y * ic);
    oc[2] = (__bf16)(c.z * ic); oc[3] = (__bf16)(c.w * ic);
    *reinterpret_cast<bf16x4*>(tab + (size_t)row0 * DIM + lane * 4) = oa;
    *reinterpret_cast<bf16x4*>(tab + (size_t)(row0 + 1) * DIM + lane * 4) = oc;
}

// ---------- Phase 2: barrier-free main loop -----------------------------------
// Wave w owns docs s*64 + w*16 + (0..15) at superstep s (0..3): every doc row
// is gathered by exactly ONE wave, per-lane, straight into A-fragments.
// Both q-halves' B-fragments live in registers (loaded once).
// Pipeline: issue loads(s) -> eval(s-1) (~1100 cyc hides gather latency) ->
// MFMA(s). No __syncthreads between token staging and the final flush.
__global__ __launch_bounds__(256, 3)
void knrm_main7(const int* __restrict__ q1t, const int* __restrict__ d1t,
                const int* __restrict__ q2t, const int* __restrict__ d2t,
                const __bf16* __restrict__ tab,
                const float* __restrict__ W0, const float* __restrict__ b0,
                const float* __restrict__ W1, const float* __restrict__ b1,
                const float* __restrict__ W2, const float* __restrict__ b2,
                float* __restrict__ lg, int B)
{
    const int b    = blockIdx.x;
    const int pair = blockIdx.y;
    const int tid  = threadIdx.x;
    const int wave = tid >> 6;
    const int lane = tid & 63;
    const int g    = lane >> 4;     // quad: k-group for A/B, row-group for C
    const int cl   = lane & 15;     // m/n row index; C col (= q-row within half)

    const int* qtok = pair ? q2t : q1t;
    const int* dtok = pair ? d2t : d1t;

    __shared__ int   dtok_s[DL];
    __shared__ int   qtok_s[QL];
    __shared__ float Sqk[QL * NK];
    __shared__ float km[NK];
    __shared__ float h0[10];
    __shared__ float h1[5];

    if (tid < QL) qtok_s[tid] = qtok[b * QL + tid];
    dtok_s[tid] = dtok[b * DL + tid];
    for (int e = tid; e < QL * NK; e += 256) Sqk[e] = 0.0f;
    if (tid < NK) km[tid] = 0.0f;
    __syncthreads();

    // ---- B fragments (query, both halves) pinned in registers:
    // lane (g,cl): B[n=cl][k=ks*32+g*8+j] -> 16 B at qrow*512 + ks*64 + g*16
    bf16x8 qf0[8], qf1[8];
    {
        const __bf16* p0 = tab + (size_t)qtok_s[cl]      * DIM + g * 8;
        const __bf16* p1 = tab + (size_t)qtok_s[16 + cl] * DIM + g * 8;
        #pragma unroll
        for (int ks = 0; ks < 8; ++ks) {
            qf0[ks] = *reinterpret_cast<const bf16x8*>(p0 + ks * 32);
            qf1[ks] = *reinterpret_cast<const bf16x8*>(p1 + ks * 32);
        }
    }
    const int qtkA = qtok_s[cl];
    const int qtkB = qtok_s[16 + cl];

    float acc[2 * NK];
    #pragma unroll
    for (int e = 0; e < 2 * NK; ++e) acc[e] = 0.0f;

    // ---- superstep 0: load A-frags (doc row wave*16+cl), MFMA
    bf16x8 af[8];
    {
        const __bf16* pa = tab + (size_t)dtok_s[wave * 16 + cl] * DIM + g * 8;
        #pragma unroll
        for (int ks = 0; ks < 8; ++ks)
            af[ks] = *reinterpret_cast<const bf16x8*>(pa + ks * 32);
    }
    f32x4 cfA = {0.0f, 0.0f, 0.0f, 0.0f};
    f32x4 cfB = {0.0f, 0.0f, 0.0f, 0.0f};
    #pragma unroll
    for (int ks = 0; ks < 8; ++ks) {
        cfA = __builtin_amdgcn_mfma_f32_16x16x32_bf16(af[ks], qf0[ks], cfA, 0, 0, 0);
        cfB = __builtin_amdgcn_mfma_f32_16x16x32_bf16(af[ks], qf1[ks], cfB, 0, 0, 0);
    }

    // ---- pipelined supersteps 1..3: load(s) -> eval(s-1) -> MFMA(s)
    for (int s = 1; s < 4; ++s) {
        const __bf16* pa = tab + (size_t)dtok_s[s * 64 + wave * 16 + cl] * DIM + g * 8;
        #pragma unroll
        for (int ks = 0; ks < 8; ++ks)
            af[ks] = *reinterpret_cast<const bf16x8*>(pa + ks * 32);

        // eval superstep s-1: cfA[i] = mm[doc=(s-1)*64+wave*16+g*4+i][q=cl],
        //                     cfB[i] = same doc, q = 16+cl
        int dbase = (s - 1) * 64 + wave * 16 + g * 4;
        #pragma unroll
        for (int i = 0; i < 4; ++i) {
            int   dtk = dtok_s[dbase + i];
            float mmA = cfA[i], mA2 = mmA * mmA;
            float mmB = cfB[i], mB2 = mmB * mmB;
            #pragma unroll
            for (int k = 0; k < KSOFT; ++k) {
                float mu = -0.95f + 0.1f * (float)k;          // compile-time
                float a1 = 100.0f * L2E * mu;
                float a0 = -50.0f * L2E * mu * mu;
                acc[k]      += EXP2F(fmaf(a1, mmA, fmaf(-50.0f * L2E, mA2, a0)));
                acc[NK + k] += EXP2F(fmaf(a1, mmB, fmaf(-50.0f * L2E, mB2, a0)));
            }
            acc[KSOFT]      += (dtk == qtkA) ? 1.0f : 0.0f;
            acc[NK + KSOFT] += (dtk == qtkB) ? 1.0f : 0.0f;
        }

        cfA = {0.0f, 0.0f, 0.0f, 0.0f};
        cfB = {0.0f, 0.0f, 0.0f, 0.0f};
        #pragma unroll
        for (int ks = 0; ks < 8; ++ks) {
            cfA = __builtin_amdgcn_mfma_f32_16x16x32_bf16(af[ks], qf0[ks], cfA, 0, 0, 0);
            cfB = __builtin_amdgcn_mfma_f32_16x16x32_bf16(af[ks], qf1[ks], cfB, 0, 0, 0);
        }
    }

    // ---- eval superstep 3
    {
        int dbase = 3 * 64 + wave * 16 + g * 4;
        #pragma unroll
        for (int i = 0; i < 4; ++i) {
            int   dtk = dtok_s[dbase + i];
            float mmA = cfA[i], mA2 = mmA * mmA;
            float mmB = cfB[i], mB2 = mmB * mmB;
            #pragma unroll
            for (int k = 0; k < KSOFT; ++k) {
                float mu = -0.95f + 0.1f * (float)k;
                float a1 = 100.0f * L2E * mu;
                float a0 = -50.0f * L2E * mu * mu;
                acc[k]      += EXP2F(fmaf(a1, mmA, fmaf(-50.0f * L2E, mA2, a0)));
                acc[NK + k] += EXP2F(fmaf(a1, mmB, fmaf(-50.0f * L2E, mB2, a0)));
            }
            acc[KSOFT]      += (dtk == qtkA) ? 1.0f : 0.0f;
            acc[NK + KSOFT] += (dtk == qtkB) ? 1.0f : 0.0f;
        }
    }

    // ---- flush: 16 lanes (4 g x 4 waves) contribute per q-row
    #pragma unroll
    for (int k = 0; k < NK; ++k) {
        atomicAdd(&Sqk[cl * NK + k],        acc[k]);
        atomicAdd(&Sqk[(16 + cl) * NK + k], acc[NK + k]);
    }
    __syncthreads();

    // ---- km[k] = sum_q log1p(Sqk[q][k])
    for (int e = tid; e < QL * NK; e += 256)
        atomicAdd(&km[e % NK], log1pf(Sqk[e]));
    __syncthreads();

    // ---- tiny MLP 21 -> 10 -> 5 -> 1
    if (tid < 10) {
        float h = b0[tid];
        #pragma unroll
        for (int k = 0; k < NK; ++k) h = fmaf(km[k], W0[tid*NK + k], h);
        h0[tid] = fmaxf(h, 0.0f);
    }
    __syncthreads();
    if (tid < 5) {
        float h = b1[tid];
        #pragma unroll
        for (int j = 0; j < 10; ++j) h = fmaf(h0[j], W1[tid*10 + j], h);
        h1[tid] = fmaxf(h, 0.0f);
    }
    __syncthreads();
    if (tid == 0) {
        float l = b2[0];
        #pragma unroll
        for (int j = 0; j < 5; ++j) l = fmaf(h1[j], W2[j], l);
        lg[pair * B + b] = l;
    }
}

__global__ void knrm_final(const float* __restrict__ lg, float* __restrict__ out, int B)
{
    int i = blockIdx.x * 256 + threadIdx.x;
    if (i < B) {
        float z = lg[i] - lg[B + i];
        out[i] = 1.0f / (1.0f + expf(-z));
    }
}

// ---------- Fallback A (R7 path, proven): LDS-staged doc tiles ----------------
__global__ __launch_bounds__(256, 4)
void knrm_main5(const int* __restrict__ q1t, const int* __restrict__ d1t,
                const int* __restrict__ q2t, const int* __restrict__ d2t,
                const __bf16* __restrict__ tab,
                const float* __restrict__ W0, const float* __restrict__ b0,
                const float* __restrict__ W1, const float* __restrict__ b1,
                const float* __restrict__ W2, const float* __restrict__ b2,
                float* __restrict__ lg, int B)
{
    const int b    = blockIdx.x;
    const int pair = blockIdx.y;
    const int tid  = threadIdx.x;
    const int wave = tid >> 6;
    const int lane = tid & 63;
    const int qt   = wave >> 1;
    const int dt   = wave & 1;
    const int g    = lane >> 4;
    const int cl   = lane & 15;
    const int hl   = lane & 31;
    const int hw   = lane >> 5;

    const int* qtok = pair ? q2t : q1t;
    const int* dtok = pair ? d2t : d1t;

    __shared__ __align__(16) __bf16 qbuf[QL * STR];
    __shared__ __align__(16) __bf16 dbuf[32 * STR];
    __shared__ float Sqk[QL * NK];
    __shared__ int   dtok_s[DL];
    __shared__ int   qtok_s[QL];
    __shared__ float km[NK];
    __shared__ float h0[10];
    __shared__ float h1[5];

    if (tid < QL) qtok_s[tid] = qtok[b * QL + tid];
    dtok_s[tid] = dtok[b * DL + tid];
    for (int e = tid; e < QL * NK; e += 256) Sqk[e] = 0.0f;
    if (tid < NK) km[tid] = 0.0f;
    __syncthreads();

    {
        bf16x8 qv[4];
        #pragma unroll
        for (int i = 0; i < 4; ++i) {
            int r = wave * 8 + i * 2 + hw;
            qv[i] = *reinterpret_cast<const bf16x8*>(
                tab + (size_t)qtok_s[r] * DIM + hl * 8);
        }
        #pragma unroll
        for (int i = 0; i < 4; ++i) {
            int r = wave * 8 + i * 2 + hw;
            *reinterpret_cast<bf16x8*>(&qbuf[r * STR + hl * 8]) = qv[i];
        }
    }

    bf16x8 dreg[4];
    #pragma unroll
    for (int i = 0; i < 4; ++i) {
        int r = wave * 8 + i * 2 + hw;
        dreg[i] = *reinterpret_cast<const bf16x8*>(
            tab + (size_t)dtok_s[r] * DIM + hl * 8);
    }

    const int myq  = qt * 16 + cl;
    const int qtk1 = qtok_s[myq];

    float acc[NK];
    #pragma unroll
    for (int k = 0; k < NK; ++k) acc[k] = 0.0f;

    for (int tile = 0; tile < 8; ++tile) {
        __syncthreads();
        #pragma unroll
        for (int i = 0; i < 4; ++i) {
            int r = wave * 8 + i * 2 + hw;
            *reinterpret_cast<bf16x8*>(&dbuf[r * STR + hl * 8]) = dreg[i];
        }
        if (tile < 7) {
            #pragma unroll
            for (int i = 0; i < 4; ++i) {
                int r = wave * 8 + i * 2 + hw;
                dreg[i] = *reinterpret_cast<const bf16x8*>(
                    tab + (size_t)dtok_s[(tile + 1) * 32 + r] * DIM + hl * 8);
            }
        }
        __syncthreads();

        f32x4 cf = {0.0f, 0.0f, 0.0f, 0.0f};
        #pragma unroll
        for (int ks = 0; ks < 8; ++ks) {
            bf16x8 dfr = *reinterpret_cast<const bf16x8*>(&dbuf[(dt*16 + cl)*STR + ks*32 + g*8]);
            bf16x8 qfr = *reinterpret_cast<const bf16x8*>(&qbuf[(qt*16 + cl)*STR + ks*32 + g*8]);
            cf = __builtin_amdgcn_mfma_f32_16x16x32_bf16(dfr, qfr, cf, 0, 0, 0);
        }

        #pragma unroll
        for (int i = 0; i < 4; ++i) {
            float mm  = cf[i];
            float mm2 = mm * mm;
            #pragma unroll
            for (int k = 0; k < KSOFT; ++k) {
                float mu = -0.95f + 0.1f * (float)k;
                float a1 = 100.0f * L2E * mu;
                float a0 = -50.0f * L2E * mu * mu;
                float arg = fmaf(a1, mm, fmaf(-50.0f * L2E, mm2, a0));
                acc[k] += EXP2F(arg);
            }
            int drow = tile*32 + dt*16 + g*4 + i;
            acc[KSOFT] += (dtok_s[drow] == qtk1) ? 1.0f : 0.0f;
        }
    }

    #pragma unroll
    for (int k = 0; k < NK; ++k)
        atomicAdd(&Sqk[myq * NK + k], acc[k]);
    __syncthreads();

    for (int e = tid; e < QL * NK; e += 256)
        atomicAdd(&km[e % NK], log1pf(Sqk[e]));
    __syncthreads();

    if (tid < 10) {
        float h = b0[tid];
        #pragma unroll
        for (int k = 0; k < NK; ++k) h = fmaf(km[k], W0[tid*NK + k], h);
        h0[tid] = fmaxf(h, 0.0f);
    }
    __syncthreads();
    if (tid < 5) {
        float h = b1[tid];
        #pragma unroll
        for (int j = 0; j < 10; ++j) h = fmaf(h0[j], W1[tid*10 + j], h);
        h1[tid] = fmaxf(h, 0.0f);
    }
    __syncthreads();
    if (tid == 0) {
        float l = b2[0];
        #pragma unroll
        for (int j = 0; j < 5; ++j) l = fmaf(h1[j], W2[j], l);
        lg[pair * B + b] = l;
    }
}

// ---------- Fallback B (monolithic): ws can't hold the bf16 table ------------
__global__ __launch_bounds__(256, 2)
void knrm_mono(const int* __restrict__ q1t, const int* __restrict__ d1t,
               const int* __restrict__ q2t, const int* __restrict__ d2t,
               const float* __restrict__ emb,
               const float* __restrict__ W0, const float* __restrict__ b0,
               const float* __restrict__ W1, const float* __restrict__ b1,
               const float* __restrict__ W2, const float* __restrict__ b2,
               float* __restrict__ out)
{
    const int b    = blockIdx.x;
    const int tid  = threadIdx.x;
    const int wave = tid >> 6;
    const int lane = tid & 63;
    const int qt   = wave >> 1;
    const int dt   = wave & 1;
    const int g    = lane >> 4;
    const int cl   = lane & 15;

    __shared__ __align__(16) __bf16 qbuf[QL * STR];
    __shared__ __align__(16) __bf16 dbuf[32 * STR];
    __shared__ float Sqk[QL * NK];
    __shared__ int   dtok_s[DL];
    __shared__ int   qtok_s[QL];
    __shared__ float km[NK];
    __shared__ float h0[10];
    __shared__ float h1[5];
    __shared__ float logit[2];

    for (int pair = 0; pair < 2; ++pair) {
        const int* qtok = pair ? q2t : q1t;
        const int* dtok = pair ? d2t : d1t;

        if (tid < QL) qtok_s[tid] = qtok[b * QL + tid];
        dtok_s[tid] = dtok[b * DL + tid];
        for (int e = tid; e < QL * NK; e += 256) Sqk[e] = 0.0f;
        if (tid < NK) km[tid] = 0.0f;
        __syncthreads();

        #pragma unroll
        for (int i = 0; i < 8; ++i) {
            int row = wave * 8 + i;
            int tok = qtok_s[row];
            float4 v = reinterpret_cast<const float4*>(emb + (size_t)tok * DIM)[lane];
            float s = v.x*v.x + v.y*v.y + v.z*v.z + v.w*v.w;
            #pragma unroll
            for (int m = 32; m; m >>= 1) s += __shfl_xor(s, m);
            float inv = rsqrtf(fmaxf(s, 1e-16f));
            bf16x4 o;
            o[0] = (__bf16)(v.x * inv); o[1] = (__bf16)(v.y * inv);
            o[2] = (__bf16)(v.z * inv); o[3] = (__bf16)(v.w * inv);
            *reinterpret_cast<bf16x4*>(&qbuf[row * STR + lane * 4]) = o;
        }

        int qtk[4];
        #pragma unroll
        for (int i = 0; i < 4; ++i) qtk[i] = qtok_s[qt * 16 + g * 4 + i];

        float acc[4 * NK];
        #pragma unroll
        for (int e = 0; e < 4 * NK; ++e) acc[e] = 0.0f;

        for (int tile = 0; tile < 8; ++tile) {
            #pragma unroll
            for (int i = 0; i < 8; ++i) {
                int r = wave * 8 + i;
                int tok = dtok_s[tile * 32 + r];
                float4 v = reinterpret_cast<const float4*>(emb + (size_t)tok * DIM)[lane];
                float s = v.x*v.x + v.y*v.y + v.z*v.z + v.w*v.w;
                #pragma unroll
                for (int m = 32; m; m >>= 1) s += __shfl_xor(s, m);
                float inv = rsqrtf(fmaxf(s, 1e-16f));
                bf16x4 o;
                o[0] = (__bf16)(v.x * inv); o[1] = (__bf16)(v.y * inv);
                o[2] = (__bf16)(v.z * inv); o[3] = (__bf16)(v.w * inv);
                *reinterpret_cast<bf16x4*>(&dbuf[r * STR + lane * 4]) = o;
            }
            __syncthreads();

            f32x4 cf = {0.0f, 0.0f, 0.0f, 0.0f};
            #pragma unroll
            for (int ks = 0; ks < 8; ++ks) {
                bf16x8 af  = *reinterpret_cast<const bf16x8*>(&qbuf[(qt*16 + cl)*STR + ks*32 + g*8]);
                bf16x8 bfr = *reinterpret_cast<const bf16x8*>(&dbuf[(dt*16 + cl)*STR + ks*32 + g*8]);
                cf = __builtin_amdgcn_mfma_f32_16x16x32_bf16(af, bfr, cf, 0, 0, 0);
            }

            int dtk = dtok_s[tile*32 + dt*16 + cl];
            #pragma unroll
            for (int i = 0; i < 4; ++i) {
                float mm  = cf[i];
                float mm2 = mm * mm;
                #pragma unroll
                for (int k = 0; k < KSOFT; ++k) {
                    float mu = -0.95f + 0.1f * (float)k;
                    float a1 = 100.0f * L2E * mu;
                    float a0 = -50.0f * L2E * mu * mu;
                    float arg = fmaf(a1, mm, fmaf(-50.0f * L2E, mm2, a0));
                    acc[i*NK + k] += EXP2F(arg);
                }
                acc[i*NK + KSOFT] += (dtk == qtk[i]) ? 1.0f : 0.0f;
            }
            __syncthreads();
        }

        #pragma unroll
        for (int i = 0; i < 4; ++i) {
            int row = qt*16 + g*4 + i;
            #pragma unroll
            for (int k = 0; k < NK; ++k)
                atomicAdd(&Sqk[row*NK + k], acc[i*NK + k]);
        }
        __syncthreads();

        for (int e = tid; e < QL * NK; e += 256)
            atomicAdd(&km[e % NK], log1pf(Sqk[e]));
        __syncthreads();

        if (tid < 10) {
            float h = b0[tid];
            #pragma unroll
            for (int k = 0; k < NK; ++k) h = fmaf(km[k], W0[tid*NK + k], h);
            h0[tid] = fmaxf(h, 0.0f);
        }
        __syncthreads();
        if (tid < 5) {
            float h = b1[tid];
            #pragma unroll
            for (int j = 0; j < 10; ++j) h = fmaf(h0[j], W1[tid*10 + j], h);
            h1[tid] = fmaxf(h, 0.0f);
        }
        __syncthreads();
        if (tid == 0) {
            float l = b2[0];
            #pragma unroll
            for (int j = 0; j < 5; ++j) l = fmaf(h1[j], W2[j], l);
            logit[pair] = l;
        }
        __syncthreads();
    }

    if (tid == 0) {
        float z = logit[0] - logit[1];
        out[b] = 1.0f / (1.0f + expf(-z));
    }
}

extern "C" void kernel_launch(void* const* d_in, const int* in_sizes, int n_in,
                              void* d_out, int out_size, void* d_ws, size_t ws_size,
                              hipStream_t stream) {
    const int*   q1  = (const int*)d_in[0];
    const int*   d1  = (const int*)d_in[1];
    const int*   q2  = (const int*)d_in[2];
    const int*   d2  = (const int*)d_in[3];
    const float* emb = (const float*)d_in[4];
    const float* W0  = (const float*)d_in[5];
    const float* b0  = (const float*)d_in[6];
    const float* W1  = (const float*)d_in[7];
    const float* b1  = (const float*)d_in[8];
    const float* W2  = (const float*)d_in[9];
    const float* b2  = (const float*)d_in[10];
    float* out = (float*)d_out;

    const int B = in_sizes[0] / QL;       // 512
    const int V = in_sizes[4] / DIM;      // 100000

    size_t tab_bytes = (size_t)V * DIM * sizeof(__bf16);
    size_t tab_al    = (tab_bytes + 255) & ~(size_t)255;
    size_t need      = tab_al + (size_t)2 * B * sizeof(float);

    if (ws_size >= need) {
        __bf16* tab = (__bf16*)d_ws;
        float*  lg  = (float*)((char*)d_ws + tab_al);

        knrm_prep<<<(V/2 + 3) / 4, 256, 0, stream>>>(emb, tab, V);
        dim3 grid(B, 2);
        knrm_main7<<<grid, 256, 0, stream>>>(q1, d1, q2, d2, tab,
                                             W0, b0, W1, b1, W2, b2, lg, B);
        knrm_final<<<(B + 255) / 256, 256, 0, stream>>>(lg, out, B);
    } else {
        knrm_mono<<<B, 256, 0, stream>>>(q1, d1, q2, d2, emb,
                                         W0, b0, W1, b1, W2, b2, out);
    }
}

// Round 10
// 241.378 us; speedup vs baseline: 1.3455x; 1.3455x over previous
//
#include <hip/hip_runtime.h>
#include <math.h>

typedef __bf16 bf16x8 __attribute__((ext_vector_type(8)));
typedef __bf16 bf16x4 __attribute__((ext_vector_type(4)));
typedef float  f32x4  __attribute__((ext_vector_type(4)));

#define QL    32
#define DL    256
#define DIM   256
#define NK    21
#define KSOFT 20
#define STR   264                 // (fallback kernel only)
#define L2E   1.4426950408889634f

#if __has_builtin(__builtin_amdgcn_exp2f)
#define EXP2F(x) __builtin_amdgcn_exp2f(x)
#else
#define EXP2F(x) exp2f(x)
#endif

// ---------- Phase 1: stream-normalize emb -> bf16 table in ws (2 rows/wave) --
// Nontemporal stores: tab is written once, read by main -> skip RFO allocate.
__global__ __launch_bounds__(256)
void knrm_prep(const float* __restrict__ emb, __bf16* __restrict__ tab, int V)
{
    const int wave = threadIdx.x >> 6;
    const int lane = threadIdx.x & 63;
    const int row0 = (blockIdx.x * 4 + wave) * 2;
    if (row0 >= V) return;                     // V even -> row0+1 also valid

    float4 a = reinterpret_cast<const float4*>(emb + (size_t)row0 * DIM)[lane];
    float4 c = reinterpret_cast<const float4*>(emb + (size_t)(row0 + 1) * DIM)[lane];
    float sa = a.x*a.x + a.y*a.y + a.z*a.z + a.w*a.w;
    float sc = c.x*c.x + c.y*c.y + c.z*c.z + c.w*c.w;
    #pragma unroll
    for (int m = 32; m; m >>= 1) { sa += __shfl_xor(sa, m); sc += __shfl_xor(sc, m); }
    float ia = rsqrtf(fmaxf(sa, 1e-16f));      // ||row|| ~16, ref eps never binds
    float ic = rsqrtf(fmaxf(sc, 1e-16f));
    bf16x4 oa, oc;
    oa[0] = (__bf16)(a.x * ia); oa[1] = (__bf16)(a.y * ia);
    oa[2] = (__bf16)(a.z * ia); oa[3] = (__bf16)(a.w * ia);
    oc[0] = (__bf16)(c.x * ic); oc[1] = (__bf16)(c.y * ic);
    oc[2] = (__bf16)(c.z * ic); oc[3] = (__bf16)(c.w * ic);
    __builtin_nontemporal_store(oa,
        reinterpret_cast<bf16x4*>(tab + (size_t)row0 * DIM + lane * 4));
    __builtin_nontemporal_store(oc,
        reinterpret_cast<bf16x4*>(tab + (size_t)(row0 + 1) * DIM + lane * 4));
}

// ---------- Phase 2: barrier-free, register-budgeted fragment pipeline --------
// Wave w: qh=w&1 (its q-half, qf[8]=32 VGPR pinned), dh=w>>1 (its doc rows).
// 8 supersteps of 16 docs: loads(s) overwrite af (dead after MFMA(s-1)),
// eval(s-1) runs on cf meanwhile, then MFMA(s). acc[21]/lane, C col == q-row.
// No __syncthreads between token staging and the final flush.
__global__ __launch_bounds__(256, 4)
void knrm_main8(const int* __restrict__ q1t, const int* __restrict__ d1t,
                const int* __restrict__ q2t, const int* __restrict__ d2t,
                const __bf16* __restrict__ tab,
                const float* __restrict__ W0, const float* __restrict__ b0,
                const float* __restrict__ W1, const float* __restrict__ b1,
                const float* __restrict__ W2, const float* __restrict__ b2,
                float* __restrict__ lg, int B)
{
    const int b    = blockIdx.x;
    const int pair = blockIdx.y;
    const int tid  = threadIdx.x;
    const int wave = tid >> 6;
    const int lane = tid & 63;
    const int g    = lane >> 4;     // k-group for A/B; C row group
    const int cl   = lane & 15;     // A/B row; C col
    const int qh   = wave & 1;      // which q-half this wave evaluates
    const int dh   = wave >> 1;     // which 16-doc slice per superstep

    const int* qtok = pair ? q2t : q1t;
    const int* dtok = pair ? d2t : d1t;

    __shared__ int   dtok_s[DL];
    __shared__ int   qtok_s[QL];
    __shared__ float Sqk[QL * NK];
    __shared__ float km[NK];
    __shared__ float h0[10];
    __shared__ float h1[5];

    if (tid < QL) qtok_s[tid] = qtok[b * QL + tid];
    dtok_s[tid] = dtok[b * DL + tid];
    for (int e = tid; e < QL * NK; e += 256) Sqk[e] = 0.0f;
    if (tid < NK) km[tid] = 0.0f;
    __syncthreads();

    // ---- this lane's q-row: pinned B-fragments (32 VGPR)
    const int myq  = qh * 16 + cl;
    const int qtk1 = qtok_s[myq];
    bf16x8 qf[8];
    {
        const __bf16* pq = tab + (size_t)qtk1 * DIM + g * 8;
        #pragma unroll
        for (int ks = 0; ks < 8; ++ks)
            qf[ks] = *reinterpret_cast<const bf16x8*>(pq + ks * 32);
    }

    float acc[NK];
    #pragma unroll
    for (int k = 0; k < NK; ++k) acc[k] = 0.0f;

    // ---- superstep 0: load A-frags (doc row dh*16+cl), MFMA
    bf16x8 af[8];
    {
        const __bf16* pa = tab + (size_t)dtok_s[dh * 16 + cl] * DIM + g * 8;
        #pragma unroll
        for (int ks = 0; ks < 8; ++ks)
            af[ks] = *reinterpret_cast<const bf16x8*>(pa + ks * 32);
    }
    f32x4 cf = {0.0f, 0.0f, 0.0f, 0.0f};
    #pragma unroll
    for (int ks = 0; ks < 8; ++ks)
        cf = __builtin_amdgcn_mfma_f32_16x16x32_bf16(af[ks], qf[ks], cf, 0, 0, 0);

    // ---- supersteps 1..7: loads(s) -> eval(s-1) -> MFMA(s)
    #pragma unroll
    for (int s = 1; s < 8; ++s) {
        const __bf16* pa = tab + (size_t)dtok_s[s * 32 + dh * 16 + cl] * DIM + g * 8;
        #pragma unroll
        for (int ks = 0; ks < 8; ++ks)
            af[ks] = *reinterpret_cast<const bf16x8*>(pa + ks * 32);

        // eval superstep s-1: cf[i] = mm[doc=(s-1)*32+dh*16+g*4+i][q=myq]
        int dbase = (s - 1) * 32 + dh * 16 + g * 4;
        #pragma unroll
        for (int i = 0; i < 4; ++i) {
            int   dtk = dtok_s[dbase + i];
            float mm  = cf[i];
            float mm2 = mm * mm;
            #pragma unroll
            for (int k = 0; k < KSOFT; ++k) {
                float mu = -0.95f + 0.1f * (float)k;          // compile-time
                float a1 = 100.0f * L2E * mu;
                float a0 = -50.0f * L2E * mu * mu;
                acc[k] += EXP2F(fmaf(a1, mm, fmaf(-50.0f * L2E, mm2, a0)));
            }
            acc[KSOFT] += (dtk == qtk1) ? 1.0f : 0.0f;   // exact kernel
        }

        cf = {0.0f, 0.0f, 0.0f, 0.0f};
        #pragma unroll
        for (int ks = 0; ks < 8; ++ks)
            cf = __builtin_amdgcn_mfma_f32_16x16x32_bf16(af[ks], qf[ks], cf, 0, 0, 0);
    }

    // ---- eval superstep 7
    {
        int dbase = 7 * 32 + dh * 16 + g * 4;
        #pragma unroll
        for (int i = 0; i < 4; ++i) {
            int   dtk = dtok_s[dbase + i];
            float mm  = cf[i];
            float mm2 = mm * mm;
            #pragma unroll
            for (int k = 0; k < KSOFT; ++k) {
                float mu = -0.95f + 0.1f * (float)k;
                float a1 = 100.0f * L2E * mu;
                float a0 = -50.0f * L2E * mu * mu;
                acc[k] += EXP2F(fmaf(a1, mm, fmaf(-50.0f * L2E, mm2, a0)));
            }
            acc[KSOFT] += (dtk == qtk1) ? 1.0f : 0.0f;
        }
    }

    // ---- flush: 8 lanes (4 g x 2 dh-waves) contribute per q-row
    #pragma unroll
    for (int k = 0; k < NK; ++k)
        atomicAdd(&Sqk[myq * NK + k], acc[k]);
    __syncthreads();

    // ---- km[k] = sum_q log1p(Sqk[q][k])
    for (int e = tid; e < QL * NK; e += 256)
        atomicAdd(&km[e % NK], log1pf(Sqk[e]));
    __syncthreads();

    // ---- tiny MLP 21 -> 10 -> 5 -> 1
    if (tid < 10) {
        float h = b0[tid];
        #pragma unroll
        for (int k = 0; k < NK; ++k) h = fmaf(km[k], W0[tid*NK + k], h);
        h0[tid] = fmaxf(h, 0.0f);
    }
    __syncthreads();
    if (tid < 5) {
        float h = b1[tid];
        #pragma unroll
        for (int j = 0; j < 10; ++j) h = fmaf(h0[j], W1[tid*10 + j], h);
        h1[tid] = fmaxf(h, 0.0f);
    }
    __syncthreads();
    if (tid == 0) {
        float l = b2[0];
        #pragma unroll
        for (int j = 0; j < 5; ++j) l = fmaf(h1[j], W2[j], l);
        lg[pair * B + b] = l;
    }
}

__global__ void knrm_final(const float* __restrict__ lg, float* __restrict__ out, int B)
{
    int i = blockIdx.x * 256 + threadIdx.x;
    if (i < B) {
        float z = lg[i] - lg[B + i];
        out[i] = 1.0f / (1.0f + expf(-z));
    }
}

// ---------- Fallback (monolithic): ws can't hold the bf16 table ---------------
__global__ __launch_bounds__(256, 2)
void knrm_mono(const int* __restrict__ q1t, const int* __restrict__ d1t,
               const int* __restrict__ q2t, const int* __restrict__ d2t,
               const float* __restrict__ emb,
               const float* __restrict__ W0, const float* __restrict__ b0,
               const float* __restrict__ W1, const float* __restrict__ b1,
               const float* __restrict__ W2, const float* __restrict__ b2,
               float* __restrict__ out)
{
    const int b    = blockIdx.x;
    const int tid  = threadIdx.x;
    const int wave = tid >> 6;
    const int lane = tid & 63;
    const int qt   = wave >> 1;
    const int dt   = wave & 1;
    const int g    = lane >> 4;
    const int cl   = lane & 15;

    __shared__ __align__(16) __bf16 qbuf[QL * STR];
    __shared__ __align__(16) __bf16 dbuf[32 * STR];
    __shared__ float Sqk[QL * NK];
    __shared__ int   dtok_s[DL];
    __shared__ int   qtok_s[QL];
    __shared__ float km[NK];
    __shared__ float h0[10];
    __shared__ float h1[5];
    __shared__ float logit[2];

    for (int pair = 0; pair < 2; ++pair) {
        const int* qtok = pair ? q2t : q1t;
        const int* dtok = pair ? d2t : d1t;

        if (tid < QL) qtok_s[tid] = qtok[b * QL + tid];
        dtok_s[tid] = dtok[b * DL + tid];
        for (int e = tid; e < QL * NK; e += 256) Sqk[e] = 0.0f;
        if (tid < NK) km[tid] = 0.0f;
        __syncthreads();

        #pragma unroll
        for (int i = 0; i < 8; ++i) {
            int row = wave * 8 + i;
            int tok = qtok_s[row];
            float4 v = reinterpret_cast<const float4*>(emb + (size_t)tok * DIM)[lane];
            float s = v.x*v.x + v.y*v.y + v.z*v.z + v.w*v.w;
            #pragma unroll
            for (int m = 32; m; m >>= 1) s += __shfl_xor(s, m);
            float inv = rsqrtf(fmaxf(s, 1e-16f));
            bf16x4 o;
            o[0] = (__bf16)(v.x * inv); o[1] = (__bf16)(v.y * inv);
            o[2] = (__bf16)(v.z * inv); o[3] = (__bf16)(v.w * inv);
            *reinterpret_cast<bf16x4*>(&qbuf[row * STR + lane * 4]) = o;
        }

        int qtk[4];
        #pragma unroll
        for (int i = 0; i < 4; ++i) qtk[i] = qtok_s[qt * 16 + g * 4 + i];

        float acc[4 * NK];
        #pragma unroll
        for (int e = 0; e < 4 * NK; ++e) acc[e] = 0.0f;

        for (int tile = 0; tile < 8; ++tile) {
            #pragma unroll
            for (int i = 0; i < 8; ++i) {
                int r = wave * 8 + i;
                int tok = dtok_s[tile * 32 + r];
                float4 v = reinterpret_cast<const float4*>(emb + (size_t)tok * DIM)[lane];
                float s = v.x*v.x + v.y*v.y + v.z*v.z + v.w*v.w;
                #pragma unroll
                for (int m = 32; m; m >>= 1) s += __shfl_xor(s, m);
                float inv = rsqrtf(fmaxf(s, 1e-16f));
                bf16x4 o;
                o[0] = (__bf16)(v.x * inv); o[1] = (__bf16)(v.y * inv);
                o[2] = (__bf16)(v.z * inv); o[3] = (__bf16)(v.w * inv);
                *reinterpret_cast<bf16x4*>(&dbuf[r * STR + lane * 4]) = o;
            }
            __syncthreads();

            f32x4 cf = {0.0f, 0.0f, 0.0f, 0.0f};
            #pragma unroll
            for (int ks = 0; ks < 8; ++ks) {
                bf16x8 af  = *reinterpret_cast<const bf16x8*>(&qbuf[(qt*16 + cl)*STR + ks*32 + g*8]);
                bf16x8 bfr = *reinterpret_cast<const bf16x8*>(&dbuf[(dt*16 + cl)*STR + ks*32 + g*8]);
                cf = __builtin_amdgcn_mfma_f32_16x16x32_bf16(af, bfr, cf, 0, 0, 0);
            }

            int dtk = dtok_s[tile*32 + dt*16 + cl];
            #pragma unroll
            for (int i = 0; i < 4; ++i) {
                float mm  = cf[i];
                float mm2 = mm * mm;
                #pragma unroll
                for (int k = 0; k < KSOFT; ++k) {
                    float mu = -0.95f + 0.1f * (float)k;
                    float a1 = 100.0f * L2E * mu;
                    float a0 = -50.0f * L2E * mu * mu;
                    float arg = fmaf(a1, mm, fmaf(-50.0f * L2E, mm2, a0));
                    acc[i*NK + k] += EXP2F(arg);
                }
                acc[i*NK + KSOFT] += (dtk == qtk[i]) ? 1.0f : 0.0f;
            }
            __syncthreads();
        }

        #pragma unroll
        for (int i = 0; i < 4; ++i) {
            int row = qt*16 + g*4 + i;
            #pragma unroll
            for (int k = 0; k < NK; ++k)
                atomicAdd(&Sqk[row*NK + k], acc[i*NK + k]);
        }
        __syncthreads();

        for (int e = tid; e < QL * NK; e += 256)
            atomicAdd(&km[e % NK], log1pf(Sqk[e]));
        __syncthreads();

        if (tid < 10) {
            float h = b0[tid];
            #pragma unroll
            for (int k = 0; k < NK; ++k) h = fmaf(km[k], W0[tid*NK + k], h);
            h0[tid] = fmaxf(h, 0.0f);
        }
        __syncthreads();
        if (tid < 5) {
            float h = b1[tid];
            #pragma unroll
            for (int j = 0; j < 10; ++j) h = fmaf(h0[j], W1[tid*10 + j], h);
            h1[tid] = fmaxf(h, 0.0f);
        }
        __syncthreads();
        if (tid == 0) {
            float l = b2[0];
            #pragma unroll
            for (int j = 0; j < 5; ++j) l = fmaf(h1[j], W2[j], l);
            logit[pair] = l;
        }
        __syncthreads();
    }

    if (tid == 0) {
        float z = logit[0] - logit[1];
        out[b] = 1.0f / (1.0f + expf(-z));
    }
}

extern "C" void kernel_launch(void* const* d_in, const int* in_sizes, int n_in,
                              void* d_out, int out_size, void* d_ws, size_t ws_size,
                              hipStream_t stream) {
    const int*   q1  = (const int*)d_in[0];
    const int*   d1  = (const int*)d_in[1];
    const int*   q2  = (const int*)d_in[2];
    const int*   d2  = (const int*)d_in[3];
    const float* emb = (const float*)d_in[4];
    const float* W0  = (const float*)d_in[5];
    const float* b0  = (const float*)d_in[6];
    const float* W1  = (const float*)d_in[7];
    const float* b1  = (const float*)d_in[8];
    const float* W2  = (const float*)d_in[9];
    const float* b2  = (const float*)d_in[10];
    float* out = (float*)d_out;

    const int B = in_sizes[0] / QL;       // 512
    const int V = in_sizes[4] / DIM;      // 100000

    size_t tab_bytes = (size_t)V * DIM * sizeof(__bf16);
    size_t tab_al    = (tab_bytes + 255) & ~(size_t)255;
    size_t need      = tab_al + (size_t)2 * B * sizeof(float);

    if (ws_size >= need) {
        __bf16* tab = (__bf16*)d_ws;
        float*  lg  = (float*)((char*)d_ws + tab_al);

        knrm_prep<<<(V/2 + 3) / 4, 256, 0, stream>>>(emb, tab, V);
        dim3 grid(B, 2);
        knrm_main8<<<grid, 256, 0, stream>>>(q1, d1, q2, d2, tab,
                                             W0, b0, W1, b1, W2, b2, lg, B);
        knrm_final<<<(B + 255) / 256, 256, 0, stream>>>(lg, out, B);
    } else {
        knrm_mono<<<B, 256, 0, stream>>>(q1, d1, q2, d2, emb,
                                         W0, b0, W1, b1, W2, b2, out);
    }
}